// Round 7
// baseline (261.909 us; speedup 1.0000x reference)
//
#include <hip/hip_runtime.h>

// Problem constants (from reference)
constexpr int B    = 1024;
constexpr int L    = 50;
constexpr int S    = 256;
constexpr int H    = 4;
constexpr int E    = 64;
constexpr int HID  = 64;
constexpr int SUPP = 10000;

// Branch-free tanh via exp2-based __expf; clamp keeps e finite. Rel err ~1e-6.
__device__ __forceinline__ float tanh_fast(float x) {
    const float xc = fminf(fmaxf(x, -15.0f), 15.0f);
    const float e  = __expf(2.0f * xc);
    return (e - 1.0f) * __builtin_amdgcn_rcpf(e + 1.0f);
}

// Broadcast lane l's value (l wave-uniform) -> v_readlane -> SGPR.
__device__ __forceinline__ float lanebc(float v, int l) {
    return __int_as_float(__builtin_amdgcn_readlane(__float_as_int(v), l));
}

// ---------------------------------------------------------------------------
// Kernel 1: fused pre-work.  256 threads (4 waves), plain __launch_bounds__.
// CODEGEN RULE (rounds 0-6 evidence): the 64-float per-lane weight column
// stays register-resident ONLY in this shape -- plain launch bounds, fully
// unrolled const-indexed consumer (VGPR=72, no spill, rounds 0/6); any of
// {__launch_bounds__(...,N) hints, float4 temps + streamed weights,
// multi-row blocking} demotes it (r1) or spills (r2/r4/r5).
//
// Round-7 deltas (inside the safe shape):
//  - 4-way accumulator split in all 64-deep dots: dependency chain 256->64cy.
//  - next-row prefetch in encode/ksupp row loops: gather of row r+1 issues
//    before row r's dot chain (VMEM latency hides under compute; occupancy
//    is only ~2 waves/SIMD so TLP can't do it for us).
//
//   blockIdx.y in {0,1}: user_fea_encode(call=y) + per-head q projection
//     (wave == head); fea never touches global memory.
//   blockIdx.y == 2:     K_supp[h][j][:] = tgt_user_emb[supp_users[j]] @ Wk[h]
//
// Algebraic simplifications (validated rounds 1-6): padded rows skipped
// (hist.sum==0 <=> l>=hlen a.s.); tanh_fast/__expf; per-wave redundant
// softmax denom.  Encoder softmax per reference: no max-subtract, padded
// rows contribute exp(0)=1, denom+1e-12.
// ---------------------------------------------------------------------------
__global__ __launch_bounds__(256) void pre_kernel(
    const int* __restrict__ x,            // (B,2)  [:,0]=user_id
    const int* __restrict__ src_his,      // (B,L)
    const int* __restrict__ src_hl,       // (B,)
    const int* __restrict__ tgt_his,      // (B,L)
    const int* __restrict__ tgt_hl,      // (B,)
    const float* __restrict__ item_emb,   // src_item_emb -- always src!
    const float* __restrict__ src_user_emb,
    const float* __restrict__ tgt_user_emb,
    const int* __restrict__ supp_users,   // (SUPP,)
    const float* __restrict__ W_att_w,    // (E,E)
    const float* __restrict__ W_att_b,    // (E,)
    const float* __restrict__ W_agg_w,    // (E,E)
    const float* __restrict__ Wq,         // (H,E,E)
    const float* __restrict__ Wk,         // (H,E,E)
    float* __restrict__ qout,             // (2,H,B,E)
    float* __restrict__ K_supp)           // (H,SUPP,E)
{
    const int tid  = threadIdx.x;
    const int lane = tid & 63;
    const int wave = tid >> 6;

    if (blockIdx.y == 2) {
        // ---------------- ksupp plane ----------------
        const int h = wave;   // wave == head
        float wcol[E];
#pragma unroll
        for (int i = 0; i < E; i++) wcol[i] = Wk[h * E * E + i * E + lane];

        // prefetch-next + 4-way chain split (gridDim.x == 1024 <= SUPP)
        int j = blockIdx.x;
        float ev = tgt_user_emb[(size_t)supp_users[j] * E + lane];
#pragma unroll 1
        while (j < SUPP) {
            const int jn = j + (int)gridDim.x;
            float evn = 0.0f;
            if (jn < SUPP)
                evn = tgt_user_emb[(size_t)supp_users[jn] * E + lane];
            float a0 = 0.f, a1 = 0.f, a2 = 0.f, a3 = 0.f;
#pragma unroll
            for (int i = 0; i < E; i += 4) {
                a0 = fmaf(lanebc(ev, i + 0), wcol[i + 0], a0);
                a1 = fmaf(lanebc(ev, i + 1), wcol[i + 1], a1);
                a2 = fmaf(lanebc(ev, i + 2), wcol[i + 2], a2);
                a3 = fmaf(lanebc(ev, i + 3), wcol[i + 3], a3);
            }
            K_supp[((size_t)h * SUPP + j) * E + lane] = (a0 + a1) + (a2 + a3);
            j = jn;
            ev = evn;
        }
        return;
    }

    // ---------------- encode + q plane ----------------
    __shared__ float sHist[L * E];
    __shared__ float sAtt[64];
    __shared__ float sPart[4][E];
    __shared__ float sOut[E];

    const int b    = blockIdx.x;
    const int call = blockIdx.y;

    const int* his = call ? tgt_his : src_his;
    const int* hl  = call ? tgt_hl  : src_hl;
    const float* user_table = call ? tgt_user_emb : src_user_emb;

    float wcol[E];
#pragma unroll
    for (int i = 0; i < E; i++) wcol[i] = W_att_w[i * E + lane];

    const int uid    = x[2 * b];
    const float uv   = user_table[(size_t)uid * E + lane];
    const float bias = W_att_b[lane];
    const int hlen   = hl[b];

    // zero logits for this wave's padded rows (no barrier needed: same wave
    // owns the same l's; everyone reads only after the __syncthreads below).
#pragma unroll 1
    for (int l = wave; l < L; l += 4)
        if (l >= hlen && lane == 0) sAtt[l] = 0.0f;

    // phase 1: own valid rows -- prefetch-next gather, stage, key-matmul
    // (4-way split chain), att logit.
    if (wave < hlen) {
        int l = wave;
        float hv = item_emb[(size_t)his[b * L + l] * E + lane];
#pragma unroll 1
        while (true) {
            const int ln = l + 4;
            float hvn = 0.0f;
            if (ln < hlen)
                hvn = item_emb[(size_t)his[b * L + ln] * E + lane];
            sHist[l * E + lane] = hv;
            float a0 = bias, a1 = 0.f, a2 = 0.f, a3 = 0.f;
#pragma unroll
            for (int i = 0; i < E; i += 4) {
                a0 = fmaf(lanebc(hv, i + 0), wcol[i + 0], a0);
                a1 = fmaf(lanebc(hv, i + 1), wcol[i + 1], a1);
                a2 = fmaf(lanebc(hv, i + 2), wcol[i + 2], a2);
                a3 = fmaf(lanebc(hv, i + 3), wcol[i + 3], a3);
            }
            float part = tanh_fast((a0 + a1) + (a2 + a3)) * uv;
#pragma unroll
            for (int off = 32; off; off >>= 1) part += __shfl_xor(part, off);
            if (lane == 0) sAtt[l] = part;
            l = ln;
            if (l >= hlen) break;
            hv = hvn;
        }
    }
    __syncthreads();

    // softmax denom, redundant per wave (no max-subtract; pads exp(0)=1).
    const float vex = (lane < L) ? __expf(sAtt[lane]) : 0.0f;
    float sden = vex;
#pragma unroll
    for (int off = 32; off; off >>= 1) sden += __shfl_xor(sden, off);
    const float rden = __builtin_amdgcn_rcpf(sden + 1e-12f);

    // ctx partials across waves; rows >= hlen contribute 0 via hist=0 -> skip.
    float c = 0.0f;
#pragma unroll 1
    for (int l = wave; l < hlen; l += 4)
        c = fmaf(lanebc(vex, l) * rden, sHist[l * E + lane], c);
    sPart[wave][lane] = c;
    __syncthreads();
    if (tid < E) sOut[tid] = sPart[0][tid] + sPart[1][tid] + sPart[2][tid] + sPart[3][tid];
    __syncthreads();

    // agg: fea = ctx @ W_agg, i-range split across waves (round-0 verbatim).
    float g = 0.0f;
#pragma unroll
    for (int k = 0; k < 16; k++) {
        const int i = wave * 16 + k;
        g += sOut[i] * W_agg_w[i * E + lane];
    }
    sPart[wave][lane] = g;
    __syncthreads();

    // fea[lane] (every wave computes it; then q projection, wave == head),
    // 4-way split chain.
    const float fval = sPart[0][lane] + sPart[1][lane] + sPart[2][lane] + sPart[3][lane];
    const float* Wqh = Wq + wave * E * E;
    float q0 = 0.f, q1 = 0.f, q2 = 0.f, q3 = 0.f;
#pragma unroll
    for (int i = 0; i < E; i += 4) {
        q0 = fmaf(lanebc(fval, i + 0), Wqh[(i + 0) * E + lane], q0);
        q1 = fmaf(lanebc(fval, i + 1), Wqh[(i + 1) * E + lane], q1);
        q2 = fmaf(lanebc(fval, i + 2), Wqh[(i + 2) * E + lane], q2);
        q3 = fmaf(lanebc(fval, i + 3), Wqh[(i + 3) * E + lane], q3);
    }
    qout[(((call * H) + wave) * B + b) * E + lane] = (q0 + q1) + (q2 + q3);
}

// ---------------------------------------------------------------------------
// Kernel 2: attention per (b,h,call).  K tile lives in REGISTERS:
// lane = (rsub = lane>>4, u = lane&15); wave w owns rows [w*64,(w+1)*64);
// kreg[i] = row (s0+4i+rsub), unit u (4 floats).  Gathers are issued as a
// batch of 16 (all in flight) before any dependent reduce.  softmax =
// jax.nn.softmax (max-subtracted).  ctx is pure-VALU FMA over the register
// tile; ctx uses k itself (reference quirk); g = ctx @ Wv[h].
//
// XCD pinning: grid flattened to 8192 blocks; (h,call) = blockIdx & 7 so all
// consumers of head h's 2.56 MB K table land on one XCD's 4 MB L2.
// ---------------------------------------------------------------------------
__global__ __launch_bounds__(256) void attn_kernel(
    const int* __restrict__ sample_idx,  // (2,H,B,S)
    const float* __restrict__ K_supp,    // (H,SUPP,E)
    const float* __restrict__ qarr,      // (2,H,B,E)
    const float* __restrict__ Wv,        // (H,E,E)
    float* __restrict__ gout)            // (2,B,H*E)
{
    __shared__ float sRed[8];
    __shared__ float sCtx[4][E];
    __shared__ float sC[E];
    __shared__ float sG[4][E];

    const int n    = blockIdx.x;
    const int xcd  = n & 7;
    const int h    = xcd >> 1;
    const int call = xcd & 1;
    const int b    = n >> 3;
    const int tid  = threadIdx.x;
    const int lane = tid & 63;
    const int wave = tid >> 6;
    const int u    = lane & 15;
    const int rsub = lane >> 4;
    const int s0   = wave * 64;

    const int* idx = sample_idx + (((call * H) + h) * B + b) * S;
    const float* Kh = K_supp + (size_t)h * SUPP * E;
    const float4 qu = *(const float4*)(qarr + ((size_t)(((call * H) + h) * B + b)) * E + 4 * u);

    // ---- batched gather: idx loads, then 16 independent row gathers ----
    int jr[16];
#pragma unroll
    for (int i = 0; i < 16; i++) jr[i] = idx[s0 + 4 * i + rsub];
    float4 kreg[16];
#pragma unroll
    for (int i = 0; i < 16; i++)
        kreg[i] = *(const float4*)(Kh + (size_t)jr[i] * E + 4 * u);

    // ---- logits: in-lane partial dot + 4-step reduce per 16-lane group ----
    float mylogit = 0.0f;
#pragma unroll
    for (int i = 0; i < 16; i++) {
        float part = kreg[i].x * qu.x + kreg[i].y * qu.y
                   + kreg[i].z * qu.z + kreg[i].w * qu.w;
#pragma unroll
        for (int off = 1; off < 16; off <<= 1) part += __shfl_xor(part, off);
        mylogit = (u == i) ? part : mylogit;   // lane holds row s0 + 4u + rsub
    }

    // ---- block softmax over 256 logits (permutation-invariant) ----
    float m = mylogit;
#pragma unroll
    for (int off = 32; off; off >>= 1) m = fmaxf(m, __shfl_xor(m, off));
    if (lane == 0) sRed[wave] = m;
    __syncthreads();
    const float mx = fmaxf(fmaxf(sRed[0], sRed[1]), fmaxf(sRed[2], sRed[3]));
    const float ex = __expf(mylogit - mx);
    float sm = ex;
#pragma unroll
    for (int off = 32; off; off >>= 1) sm += __shfl_xor(sm, off);
    if (lane == 0) sRed[4 + wave] = sm;
    __syncthreads();
    const float denom = sRed[4] + sRed[5] + sRed[6] + sRed[7];
    const float pval = ex / denom;   // weight of row s0 + 4u + rsub

    // ---- ctx: pure-VALU FMA over register tile ----
    // row s0+4i+rsub's weight lives at lane 16*rsub + i
    float4 cacc = make_float4(0.0f, 0.0f, 0.0f, 0.0f);
#pragma unroll
    for (int i = 0; i < 16; i++) {
        const float p = __shfl(pval, (lane & 48) + i);
        cacc.x += p * kreg[i].x;
        cacc.y += p * kreg[i].y;
        cacc.z += p * kreg[i].z;
        cacc.w += p * kreg[i].w;
    }
    // combine across rsub groups (lanes l, l^16, l^32, l^48 share unit u)
#pragma unroll
    for (int off = 16; off <= 32; off <<= 1) {
        cacc.x += __shfl_xor(cacc.x, off);
        cacc.y += __shfl_xor(cacc.y, off);
        cacc.z += __shfl_xor(cacc.z, off);
        cacc.w += __shfl_xor(cacc.w, off);
    }
    if (lane < 16) *(float4*)(&sCtx[wave][u * 4]) = cacc;
    __syncthreads();
    if (wave == 0) {
        sC[lane] = sCtx[0][lane] + sCtx[1][lane] + sCtx[2][lane] + sCtx[3][lane];
    }
    __syncthreads();

    // ---- g = ctx @ Wv[h], c-range split across waves ----
    const float* Wvh = Wv + h * E * E;
    float g = 0.0f;
#pragma unroll
    for (int k = 0; k < 16; k++) {
        const int c = wave * 16 + k;
        g += sC[c] * Wvh[c * E + lane];
    }
    sG[wave][lane] = g;
    __syncthreads();
    if (wave == 0) {
        gout[((size_t)(call * B) + b) * (H * E) + h * E + lane] =
            sG[0][lane] + sG[1][lane] + sG[2][lane] + sG[3][lane];
    }
}

// ---------------------------------------------------------------------------
// Kernel 3: W_out projection + final MLP + all four outputs.
// out layout: [output(B) | x3(B) | out_emb_s(B*E) | x2(B*E)]
// ---------------------------------------------------------------------------
__global__ __launch_bounds__(256) void final_kernel(
    const int* __restrict__ x,             // (B,2) [:,1]=item_id
    const float* __restrict__ tgt_item_emb,
    const float* __restrict__ gsrc,        // (B, H*E) -> user_emb path
    const float* __restrict__ gtgt,        // (B, H*E) -> hybrid path
    const float* __restrict__ W_out,       // (H*E, E)
    const float* __restrict__ l1_w,        // (2E, HID)
    const float* __restrict__ l1_b,        // (HID,)
    const float* __restrict__ l2_w,        // (HID, E)
    const float* __restrict__ l2_b,        // (E,)
    const float* __restrict__ l3_w,        // (E,1)
    const float* __restrict__ l3_b,        // (1,)
    float* __restrict__ out)
{
    __shared__ float sPart[4][E];
    __shared__ float sHyb[E];
    __shared__ float sItem[E];
    __shared__ float sX1[HID];

    const int b    = blockIdx.x;
    const int tid  = threadIdx.x;
    const int lane = tid & 63;
    const int wave = tid >> 6;

    if (tid < E) {
        const int item = x[2 * b + 1];
        sItem[tid] = tgt_item_emb[(size_t)item * E + tid];
    }

    const float* grow = (wave < 2) ? (gsrc + (size_t)b * (H * E))
                                   : (gtgt + (size_t)b * (H * E));
    const int i0 = (wave & 1) * 128;
    {
        const float4* g4 = (const float4*)(grow + i0);
        float a0 = 0.0f, a1 = 0.0f, a2 = 0.0f, a3 = 0.0f;
#pragma unroll
        for (int k = 0; k < 32; k++) {
            const float4 v = g4[k];
            const float* wr = W_out + (i0 + 4 * k) * E + lane;
            a0 += v.x * wr[0];
            a1 += v.y * wr[E];
            a2 += v.z * wr[2 * E];
            a3 += v.w * wr[3 * E];
        }
        sPart[wave][lane] = (a0 + a1) + (a2 + a3);
    }
    __syncthreads();

    if (wave == 0) {
        const float ue = sPart[0][lane] + sPart[1][lane];
        const float prod = ue * sItem[lane];
        out[2 * B + b * E + lane] = prod;  // out_emb_s
        float s = prod;
#pragma unroll
        for (int off = 32; off; off >>= 1) s += __shfl_xor(s, off);
        if (lane == 0) out[b] = s;         // output
    }
    if (wave == 1) {
        sHyb[lane] = sPart[2][lane] + sPart[3][lane];
    }
    __syncthreads();

    // l1: 128-deep sum split across 4 waves (waves 0,1: hybrid; 2,3: item)
    float a1 = 0.0f;
#pragma unroll
    for (int k = 0; k < 32; k++) {
        const int i = wave * 32 + k;
        const float v = (i < 64) ? sHyb[i] : sItem[i - 64];
        a1 += v * l1_w[i * HID + lane];
    }
    sPart[wave][lane] = a1;
    __syncthreads();

    if (wave == 0) {
        const float a = l1_b[lane] + sPart[0][lane] + sPart[1][lane]
                      + sPart[2][lane] + sPart[3][lane];
        sX1[lane] = tanh_fast(a);
    }
    __syncthreads();

    if (wave == 0) {
        float a = l2_b[lane];
#pragma unroll
        for (int i = 0; i < HID; i++) a += sX1[i] * l2_w[i * E + lane];
        const float x2 = tanh_fast(a);
        out[2 * B + B * E + b * E + lane] = x2;  // x2_t
        float p = x2 * l3_w[lane];
#pragma unroll
        for (int off = 32; off; off >>= 1) p += __shfl_xor(p, off);
        if (lane == 0) out[B + b] = p + l3_b[0]; // x3_t
    }
}

// ---------------------------------------------------------------------------
extern "C" void kernel_launch(void* const* d_in, const int* in_sizes, int n_in,
                              void* d_out, int out_size, void* d_ws, size_t ws_size,
                              hipStream_t stream) {
    const int*   x            = (const int*)d_in[0];
    const int*   src_his      = (const int*)d_in[1];
    const int*   src_hl       = (const int*)d_in[2];
    const int*   tgt_his      = (const int*)d_in[3];
    const int*   tgt_hl       = (const int*)d_in[4];
    const int*   sample_idx   = (const int*)d_in[5];
    const int*   supp_users   = (const int*)d_in[6];
    const float* src_user_emb = (const float*)d_in[7];
    const float* src_item_emb = (const float*)d_in[8];
    const float* tgt_user_emb = (const float*)d_in[9];
    const float* tgt_item_emb = (const float*)d_in[10];
    const float* W_att_w      = (const float*)d_in[11];
    const float* W_att_b      = (const float*)d_in[12];
    const float* W_agg_w      = (const float*)d_in[13];
    const float* Wq           = (const float*)d_in[14];
    const float* Wk           = (const float*)d_in[15];
    const float* Wv           = (const float*)d_in[16];
    const float* W_out        = (const float*)d_in[17];
    const float* l1_w         = (const float*)d_in[18];
    const float* l1_b         = (const float*)d_in[19];
    const float* l2_w         = (const float*)d_in[20];
    const float* l2_b         = (const float*)d_in[21];
    const float* l3_w         = (const float*)d_in[22];
    const float* l3_b         = (const float*)d_in[23];

    float* ws      = (float*)d_ws;
    float* qarr    = ws;                                  // 2*H*B*E
    float* K_supp  = qarr + 2 * H * B * E;                // H*SUPP*E
    float* garr    = K_supp + H * SUPP * E;               // 2*B*H*E
    float* out     = (float*)d_out;

    pre_kernel<<<dim3(B, 3), 256, 0, stream>>>(
        x, src_his, src_hl, tgt_his, tgt_hl, src_item_emb,
        src_user_emb, tgt_user_emb, supp_users,
        W_att_w, W_att_b, W_agg_w, Wq, Wk, qarr, K_supp);
    attn_kernel<<<dim3(B * H * 2), 256, 0, stream>>>(
        sample_idx, K_supp, qarr, Wv, garr);
    final_kernel<<<dim3(B), 256, 0, stream>>>(
        x, tgt_item_emb, garr, garr + B * H * E, W_out,
        l1_w, l1_b, l2_w, l2_b, l3_w, l3_b, out);
}

// Round 8
// 254.775 us; speedup vs baseline: 1.0280x; 1.0280x over previous
//
#include <hip/hip_runtime.h>

// Problem constants (from reference)
constexpr int B    = 1024;
constexpr int L    = 50;
constexpr int S    = 256;
constexpr int H    = 4;
constexpr int E    = 64;
constexpr int HID  = 64;
constexpr int SUPP = 10000;

// Branch-free tanh via exp2-based __expf; clamp keeps e finite. Rel err ~1e-6.
__device__ __forceinline__ float tanh_fast(float x) {
    const float xc = fminf(fmaxf(x, -15.0f), 15.0f);
    const float e  = __expf(2.0f * xc);
    return (e - 1.0f) * __builtin_amdgcn_rcpf(e + 1.0f);
}

// Broadcast lane l's value (l wave-uniform) -> v_readlane -> SGPR.
__device__ __forceinline__ float lanebc(float v, int l) {
    return __int_as_float(__builtin_amdgcn_readlane(__float_as_int(v), l));
}

// ---------------------------------------------------------------------------
// Kernel 1: fused pre-work.  256 threads (4 waves), plain __launch_bounds__.
// CODEGEN LEDGER (r0-r7): wcol[64] register-resident requires plain launch
// bounds + fully-unrolled const-indexed consumer (r0/r6/r7: VGPR=72, no
// spill).  r1 (VGPR budget 60): demoted to global reloads.  r2/r4: blocked
// multi-row accumulators -> 256/128 VGPR + scratch.  r5: float4-LDS consumer
// + __launch_bounds__(256,4) -> allocator targeted 64 VGPR, spilled 444MB.
// THIS ROUND'S EXPERIMENT: float4-LDS consumer + wcol + PLAIN bounds (the
// untested cell).  Dot becomes 16x ds_read_b128 (uniform-addr broadcast,
// LGKM pipe) + 64 FMA -- VALU issue per row ~halves vs 64 readlane + 64 FMA,
// and the loads overlap the FMA stream.  Spill tripwire: WRITE_SIZE >> 12MB.
//
//   blockIdx.y in {0,1}: user_fea_encode(call=y) + per-head q projection
//     (wave == head); fea never touches global memory.
//   blockIdx.y == 2:     K_supp[h][j][:] = tgt_user_emb[supp_users[j]] @ Wk[h]
//
// Algebraic simplifications (validated r1-r7): padded rows skipped
// (hist.sum==0 <=> l>=hlen a.s. for Gaussian embeddings); tanh_fast/__expf;
// per-wave redundant softmax denom.  Encoder softmax per reference: no
// max-subtract, padded rows contribute exp(0)=1, denom+1e-12.
// ---------------------------------------------------------------------------
__global__ __launch_bounds__(256) void pre_kernel(
    const int* __restrict__ x,            // (B,2)  [:,0]=user_id
    const int* __restrict__ src_his,      // (B,L)
    const int* __restrict__ src_hl,       // (B,)
    const int* __restrict__ tgt_his,      // (B,L)
    const int* __restrict__ tgt_hl,       // (B,)
    const float* __restrict__ item_emb,   // src_item_emb -- always src!
    const float* __restrict__ src_user_emb,
    const float* __restrict__ tgt_user_emb,
    const int* __restrict__ supp_users,   // (SUPP,)
    const float* __restrict__ W_att_w,    // (E,E)
    const float* __restrict__ W_att_b,    // (E,)
    const float* __restrict__ W_agg_w,    // (E,E)
    const float* __restrict__ Wq,         // (H,E,E)
    const float* __restrict__ Wk,         // (H,E,E)
    float* __restrict__ qout,             // (2,H,B,E)
    float* __restrict__ K_supp)           // (H,SUPP,E)
{
    const int tid  = threadIdx.x;
    const int lane = tid & 63;
    const int wave = tid >> 6;

    if (blockIdx.y == 2) {
        // ---------------- ksupp plane ----------------
        // wave == head.  Row ev staged into a per-wave LDS slot (same-wave
        // write->read, compiler-ordered, no barriers), consumed as uniform
        // float4 broadcasts against register-resident Wk column.
        __shared__ __align__(16) float sEvw[4][E];
        const int h = wave;
        float wcol[E];
#pragma unroll
        for (int i = 0; i < E; i++) wcol[i] = Wk[h * E * E + i * E + lane];

        int j = blockIdx.x;
        float ev = tgt_user_emb[(size_t)supp_users[j] * E + lane];
#pragma unroll 1
        while (j < SUPP) {
            const int jn = j + (int)gridDim.x;
            float evn = 0.0f;
            if (jn < SUPP)
                evn = tgt_user_emb[(size_t)supp_users[jn] * E + lane];
            sEvw[wave][lane] = ev;
            const float4* e4 = (const float4*)&sEvw[wave][0];
            float a0 = 0.f, a1 = 0.f, a2 = 0.f, a3 = 0.f;
#pragma unroll
            for (int k = 0; k < 16; k++) {
                const float4 v = e4[k];   // uniform addr -> LDS broadcast
                a0 = fmaf(v.x, wcol[4 * k + 0], a0);
                a1 = fmaf(v.y, wcol[4 * k + 1], a1);
                a2 = fmaf(v.z, wcol[4 * k + 2], a2);
                a3 = fmaf(v.w, wcol[4 * k + 3], a3);
            }
            K_supp[((size_t)h * SUPP + j) * E + lane] = (a0 + a1) + (a2 + a3);
            j = jn;
            ev = evn;
        }
        return;
    }

    // ---------------- encode + q plane ----------------
    __shared__ __align__(16) float sHist[L * E];
    __shared__ float sAtt[64];
    __shared__ float sPart[4][E];
    __shared__ float sOut[E];

    const int b    = blockIdx.x;
    const int call = blockIdx.y;

    const int* his = call ? tgt_his : src_his;
    const int* hl  = call ? tgt_hl  : src_hl;
    const float* user_table = call ? tgt_user_emb : src_user_emb;

    float wcol[E];
#pragma unroll
    for (int i = 0; i < E; i++) wcol[i] = W_att_w[i * E + lane];

    const int uid    = x[2 * b];
    const float uv   = user_table[(size_t)uid * E + lane];
    const float bias = W_att_b[lane];
    const int hlen   = hl[b];

    // zero logits for this wave's padded rows.
#pragma unroll 1
    for (int l = wave; l < L; l += 4)
        if (l >= hlen && lane == 0) sAtt[l] = 0.0f;

    // phase 1: own valid rows -- prefetch-next gather; stage row distributed;
    // read it back as uniform float4 broadcasts (LDS transpose-broadcast)
    // against register wcol; 4-way split accumulator chain; att logit.
    if (wave < hlen) {
        int l = wave;
        float hv = item_emb[(size_t)his[b * L + l] * E + lane];
#pragma unroll 1
        while (true) {
            const int ln = l + 4;
            float hvn = 0.0f;
            if (ln < hlen)
                hvn = item_emb[(size_t)his[b * L + ln] * E + lane];
            sHist[l * E + lane] = hv;
            const float4* hrow = (const float4*)&sHist[l * E];
            float a0 = bias, a1 = 0.f, a2 = 0.f, a3 = 0.f;
#pragma unroll
            for (int k = 0; k < 16; k++) {
                const float4 h4 = hrow[k];   // uniform addr -> LDS broadcast
                a0 = fmaf(h4.x, wcol[4 * k + 0], a0);
                a1 = fmaf(h4.y, wcol[4 * k + 1], a1);
                a2 = fmaf(h4.z, wcol[4 * k + 2], a2);
                a3 = fmaf(h4.w, wcol[4 * k + 3], a3);
            }
            float part = tanh_fast((a0 + a1) + (a2 + a3)) * uv;
#pragma unroll
            for (int off = 32; off; off >>= 1) part += __shfl_xor(part, off);
            if (lane == 0) sAtt[l] = part;
            l = ln;
            if (l >= hlen) break;
            hv = hvn;
        }
    }
    __syncthreads();

    // softmax denom, redundant per wave (no max-subtract; pads exp(0)=1).
    const float vex = (lane < L) ? __expf(sAtt[lane]) : 0.0f;
    float sden = vex;
#pragma unroll
    for (int off = 32; off; off >>= 1) sden += __shfl_xor(sden, off);
    const float rden = __builtin_amdgcn_rcpf(sden + 1e-12f);

    // ctx partials across waves; rows >= hlen contribute 0 via hist=0 -> skip.
    float c = 0.0f;
#pragma unroll 1
    for (int l = wave; l < hlen; l += 4)
        c = fmaf(lanebc(vex, l) * rden, sHist[l * E + lane], c);
    sPart[wave][lane] = c;
    __syncthreads();
    if (tid < E) sOut[tid] = sPart[0][tid] + sPart[1][tid] + sPart[2][tid] + sPart[3][tid];
    __syncthreads();

    // agg: fea = ctx @ W_agg, i-range split across waves (round-0 verbatim).
    float g = 0.0f;
#pragma unroll
    for (int k = 0; k < 16; k++) {
        const int i = wave * 16 + k;
        g += sOut[i] * W_agg_w[i * E + lane];
    }
    sPart[wave][lane] = g;
    __syncthreads();

    // fea[lane] (every wave computes it; then q projection, wave == head),
    // 4-way split chain (readlane form -- once per block, not hot).
    const float fval = sPart[0][lane] + sPart[1][lane] + sPart[2][lane] + sPart[3][lane];
    const float* Wqh = Wq + wave * E * E;
    float q0 = 0.f, q1 = 0.f, q2 = 0.f, q3 = 0.f;
#pragma unroll
    for (int i = 0; i < E; i += 4) {
        q0 = fmaf(lanebc(fval, i + 0), Wqh[(i + 0) * E + lane], q0);
        q1 = fmaf(lanebc(fval, i + 1), Wqh[(i + 1) * E + lane], q1);
        q2 = fmaf(lanebc(fval, i + 2), Wqh[(i + 2) * E + lane], q2);
        q3 = fmaf(lanebc(fval, i + 3), Wqh[(i + 3) * E + lane], q3);
    }
    qout[(((call * H) + wave) * B + b) * E + lane] = (q0 + q1) + (q2 + q3);
}

// ---------------------------------------------------------------------------
// Kernel 2: attention per (b,h,call).  K tile lives in REGISTERS:
// lane = (rsub = lane>>4, u = lane&15); wave w owns rows [w*64,(w+1)*64);
// kreg[i] = row (s0+4i+rsub), unit u (4 floats).  Gathers are issued as a
// batch of 16 (all in flight) before any dependent reduce.  softmax =
// jax.nn.softmax (max-subtracted).  ctx is pure-VALU FMA over the register
// tile; ctx uses k itself (reference quirk); g = ctx @ Wv[h].
//
// XCD pinning: grid flattened to 8192 blocks; (h,call) = blockIdx & 7 so all
// consumers of head h's 2.56 MB K table land on one XCD's 4 MB L2.
// ---------------------------------------------------------------------------
__global__ __launch_bounds__(256) void attn_kernel(
    const int* __restrict__ sample_idx,  // (2,H,B,S)
    const float* __restrict__ K_supp,    // (H,SUPP,E)
    const float* __restrict__ qarr,      // (2,H,B,E)
    const float* __restrict__ Wv,        // (H,E,E)
    float* __restrict__ gout)            // (2,B,H*E)
{
    __shared__ float sRed[8];
    __shared__ float sCtx[4][E];
    __shared__ float sC[E];
    __shared__ float sG[4][E];

    const int n    = blockIdx.x;
    const int xcd  = n & 7;
    const int h    = xcd >> 1;
    const int call = xcd & 1;
    const int b    = n >> 3;
    const int tid  = threadIdx.x;
    const int lane = tid & 63;
    const int wave = tid >> 6;
    const int u    = lane & 15;
    const int rsub = lane >> 4;
    const int s0   = wave * 64;

    const int* idx = sample_idx + (((call * H) + h) * B + b) * S;
    const float* Kh = K_supp + (size_t)h * SUPP * E;
    const float4 qu = *(const float4*)(qarr + ((size_t)(((call * H) + h) * B + b)) * E + 4 * u);

    // ---- batched gather: idx loads, then 16 independent row gathers ----
    int jr[16];
#pragma unroll
    for (int i = 0; i < 16; i++) jr[i] = idx[s0 + 4 * i + rsub];
    float4 kreg[16];
#pragma unroll
    for (int i = 0; i < 16; i++)
        kreg[i] = *(const float4*)(Kh + (size_t)jr[i] * E + 4 * u);

    // ---- logits: in-lane partial dot + 4-step reduce per 16-lane group ----
    float mylogit = 0.0f;
#pragma unroll
    for (int i = 0; i < 16; i++) {
        float part = kreg[i].x * qu.x + kreg[i].y * qu.y
                   + kreg[i].z * qu.z + kreg[i].w * qu.w;
#pragma unroll
        for (int off = 1; off < 16; off <<= 1) part += __shfl_xor(part, off);
        mylogit = (u == i) ? part : mylogit;   // lane holds row s0 + 4u + rsub
    }

    // ---- block softmax over 256 logits (permutation-invariant) ----
    float m = mylogit;
#pragma unroll
    for (int off = 32; off; off >>= 1) m = fmaxf(m, __shfl_xor(m, off));
    if (lane == 0) sRed[wave] = m;
    __syncthreads();
    const float mx = fmaxf(fmaxf(sRed[0], sRed[1]), fmaxf(sRed[2], sRed[3]));
    const float ex = __expf(mylogit - mx);
    float sm = ex;
#pragma unroll
    for (int off = 32; off; off >>= 1) sm += __shfl_xor(sm, off);
    if (lane == 0) sRed[4 + wave] = sm;
    __syncthreads();
    const float denom = sRed[4] + sRed[5] + sRed[6] + sRed[7];
    const float pval = ex / denom;   // weight of row s0 + 4u + rsub

    // ---- ctx: pure-VALU FMA over register tile ----
    // row s0+4i+rsub's weight lives at lane 16*rsub + i
    float4 cacc = make_float4(0.0f, 0.0f, 0.0f, 0.0f);
#pragma unroll
    for (int i = 0; i < 16; i++) {
        const float p = __shfl(pval, (lane & 48) + i);
        cacc.x += p * kreg[i].x;
        cacc.y += p * kreg[i].y;
        cacc.z += p * kreg[i].z;
        cacc.w += p * kreg[i].w;
    }
    // combine across rsub groups (lanes l, l^16, l^32, l^48 share unit u)
#pragma unroll
    for (int off = 16; off <= 32; off <<= 1) {
        cacc.x += __shfl_xor(cacc.x, off);
        cacc.y += __shfl_xor(cacc.y, off);
        cacc.z += __shfl_xor(cacc.z, off);
        cacc.w += __shfl_xor(cacc.w, off);
    }
    if (lane < 16) *(float4*)(&sCtx[wave][u * 4]) = cacc;
    __syncthreads();
    if (wave == 0) {
        sC[lane] = sCtx[0][lane] + sCtx[1][lane] + sCtx[2][lane] + sCtx[3][lane];
    }
    __syncthreads();

    // ---- g = ctx @ Wv[h], c-range split across waves ----
    const float* Wvh = Wv + h * E * E;
    float g = 0.0f;
#pragma unroll
    for (int k = 0; k < 16; k++) {
        const int c = wave * 16 + k;
        g += sC[c] * Wvh[c * E + lane];
    }
    sG[wave][lane] = g;
    __syncthreads();
    if (wave == 0) {
        gout[((size_t)(call * B) + b) * (H * E) + h * E + lane] =
            sG[0][lane] + sG[1][lane] + sG[2][lane] + sG[3][lane];
    }
}

// ---------------------------------------------------------------------------
// Kernel 3: W_out projection + final MLP + all four outputs.
// out layout: [output(B) | x3(B) | out_emb_s(B*E) | x2(B*E)]
// ---------------------------------------------------------------------------
__global__ __launch_bounds__(256) void final_kernel(
    const int* __restrict__ x,             // (B,2) [:,1]=item_id
    const float* __restrict__ tgt_item_emb,
    const float* __restrict__ gsrc,        // (B, H*E) -> user_emb path
    const float* __restrict__ gtgt,        // (B, H*E) -> hybrid path
    const float* __restrict__ W_out,       // (H*E, E)
    const float* __restrict__ l1_w,        // (2E, HID)
    const float* __restrict__ l1_b,        // (HID,)
    const float* __restrict__ l2_w,        // (HID, E)
    const float* __restrict__ l2_b,        // (E,)
    const float* __restrict__ l3_w,        // (E,1)
    const float* __restrict__ l3_b,        // (1,)
    float* __restrict__ out)
{
    __shared__ float sPart[4][E];
    __shared__ float sHyb[E];
    __shared__ float sItem[E];
    __shared__ float sX1[HID];

    const int b    = blockIdx.x;
    const int tid  = threadIdx.x;
    const int lane = tid & 63;
    const int wave = tid >> 6;

    if (tid < E) {
        const int item = x[2 * b + 1];
        sItem[tid] = tgt_item_emb[(size_t)item * E + tid];
    }

    const float* grow = (wave < 2) ? (gsrc + (size_t)b * (H * E))
                                   : (gtgt + (size_t)b * (H * E));
    const int i0 = (wave & 1) * 128;
    {
        const float4* g4 = (const float4*)(grow + i0);
        float a0 = 0.0f, a1 = 0.0f, a2 = 0.0f, a3 = 0.0f;
#pragma unroll
        for (int k = 0; k < 32; k++) {
            const float4 v = g4[k];
            const float* wr = W_out + (i0 + 4 * k) * E + lane;
            a0 += v.x * wr[0];
            a1 += v.y * wr[E];
            a2 += v.z * wr[2 * E];
            a3 += v.w * wr[3 * E];
        }
        sPart[wave][lane] = (a0 + a1) + (a2 + a3);
    }
    __syncthreads();

    if (wave == 0) {
        const float ue = sPart[0][lane] + sPart[1][lane];
        const float prod = ue * sItem[lane];
        out[2 * B + b * E + lane] = prod;  // out_emb_s
        float s = prod;
#pragma unroll
        for (int off = 32; off; off >>= 1) s += __shfl_xor(s, off);
        if (lane == 0) out[b] = s;         // output
    }
    if (wave == 1) {
        sHyb[lane] = sPart[2][lane] + sPart[3][lane];
    }
    __syncthreads();

    // l1: 128-deep sum split across 4 waves (waves 0,1: hybrid; 2,3: item)
    float a1 = 0.0f;
#pragma unroll
    for (int k = 0; k < 32; k++) {
        const int i = wave * 32 + k;
        const float v = (i < 64) ? sHyb[i] : sItem[i - 64];
        a1 += v * l1_w[i * HID + lane];
    }
    sPart[wave][lane] = a1;
    __syncthreads();

    if (wave == 0) {
        const float a = l1_b[lane] + sPart[0][lane] + sPart[1][lane]
                      + sPart[2][lane] + sPart[3][lane];
        sX1[lane] = tanh_fast(a);
    }
    __syncthreads();

    if (wave == 0) {
        float a = l2_b[lane];
#pragma unroll
        for (int i = 0; i < HID; i++) a += sX1[i] * l2_w[i * E + lane];
        const float x2 = tanh_fast(a);
        out[2 * B + B * E + b * E + lane] = x2;  // x2_t
        float p = x2 * l3_w[lane];
#pragma unroll
        for (int off = 32; off; off >>= 1) p += __shfl_xor(p, off);
        if (lane == 0) out[B + b] = p + l3_b[0]; // x3_t
    }
}

// ---------------------------------------------------------------------------
extern "C" void kernel_launch(void* const* d_in, const int* in_sizes, int n_in,
                              void* d_out, int out_size, void* d_ws, size_t ws_size,
                              hipStream_t stream) {
    const int*   x            = (const int*)d_in[0];
    const int*   src_his      = (const int*)d_in[1];
    const int*   src_hl       = (const int*)d_in[2];
    const int*   tgt_his      = (const int*)d_in[3];
    const int*   tgt_hl       = (const int*)d_in[4];
    const int*   sample_idx   = (const int*)d_in[5];
    const int*   supp_users   = (const int*)d_in[6];
    const float* src_user_emb = (const float*)d_in[7];
    const float* src_item_emb = (const float*)d_in[8];
    const float* tgt_user_emb = (const float*)d_in[9];
    const float* tgt_item_emb = (const float*)d_in[10];
    const float* W_att_w      = (const float*)d_in[11];
    const float* W_att_b      = (const float*)d_in[12];
    const float* W_agg_w      = (const float*)d_in[13];
    const float* Wq           = (const float*)d_in[14];
    const float* Wk           = (const float*)d_in[15];
    const float* Wv           = (const float*)d_in[16];
    const float* W_out        = (const float*)d_in[17];
    const float* l1_w         = (const float*)d_in[18];
    const float* l1_b         = (const float*)d_in[19];
    const float* l2_w         = (const float*)d_in[20];
    const float* l2_b         = (const float*)d_in[21];
    const float* l3_w         = (const float*)d_in[22];
    const float* l3_b         = (const float*)d_in[23];

    float* ws      = (float*)d_ws;
    float* qarr    = ws;                                  // 2*H*B*E
    float* K_supp  = qarr + 2 * H * B * E;                // H*SUPP*E
    float* garr    = K_supp + H * SUPP * E;               // 2*B*H*E
    float* out     = (float*)d_out;

    pre_kernel<<<dim3(B, 3), 256, 0, stream>>>(
        x, src_his, src_hl, tgt_his, tgt_hl, src_item_emb,
        src_user_emb, tgt_user_emb, supp_users,
        W_att_w, W_att_b, W_agg_w, Wq, Wk, qarr, K_supp);
    attn_kernel<<<dim3(B * H * 2), 256, 0, stream>>>(
        sample_idx, K_supp, qarr, Wv, garr);
    final_kernel<<<dim3(B), 256, 0, stream>>>(
        x, tgt_item_emb, garr, garr + B * H * E, W_out,
        l1_w, l1_b, l2_w, l2_b, l3_w, l3_b, out);
}